// Round 1
// baseline (119.472 us; speedup 1.0000x reference)
//
#include <hip/hip_runtime.h>

// Problem constants (match reference setup_inputs)
#define VOCAB   32000
#define D_MODEL 512
#define BATCH   8
#define SEQ     4096

// -log2(10000)/256  : invfreq(d) = 10000^(-d/256) = exp2(d * NEG_L2_1E4_O256)
#define NEG_L2_1E4_O256 (-13.287712379549449f / 256.0f)
#define INV_2PI          0.15915494309189535f

// Native HIP float4 is a class type; clang's nontemporal builtins want a real
// vector type, so use an ext_vector float4.
typedef float f4 __attribute__((ext_vector_type(4)));

// One block per sequence position s (4096 blocks), 128 threads.
// Thread t owns float4 column t (d = 4t..4t+3). PE computed once per (s,d),
// reused across all 8 batches.
//
// vs previous version:
//  - all 8 gather loads issued before any use (max memory-level parallelism;
//    PE trig overlaps the loads in flight)
//  - hardware trig: v_fract + v_sin/v_cos (revolutions) instead of ocml
//    sinf/cosf large-arg reduction (~50 instrs -> 3 per PE value)
//  - nontemporal stores: output is write-once, keep table lines in L2
__global__ __launch_bounds__(128) void emb_pe_kernel(
    const int*   __restrict__ tokens,   // [BATCH, SEQ] int32
    const float* __restrict__ table,    // [VOCAB, D_MODEL] fp32
    float*       __restrict__ out)      // [BATCH, SEQ, D_MODEL] fp32
{
    const int s   = blockIdx.x;      // 0..SEQ-1
    const int tid = threadIdx.x;     // 0..127
    const int d0  = tid << 2;        // first of 4 d-indices

    // --- tokens: block-uniform addresses -> scalar loads; issue early ---
    int tok[BATCH];
#pragma unroll
    for (int b = 0; b < BATCH; ++b)
        tok[b] = tokens[b * SEQ + s];

    // --- gather all 8 embedding rows; independent loads, all in flight ---
    const f4* tbl4 = (const f4*)table;
    f4 e[BATCH];
#pragma unroll
    for (int b = 0; b < BATCH; ++b)
        e[b] = tbl4[tok[b] * (D_MODEL / 4) + tid];

    // --- positional encoding for (s, d0..d0+3) while loads are in flight ---
    // angle = s * 10000^(-d/256); hw sin/cos take revolutions, fract-reduced.
    const float sf = (float)s;
    float pe[4];
#pragma unroll
    for (int j = 0; j < 4; ++j) {
        const int d = d0 + j;
        const float invf = __builtin_amdgcn_exp2f((float)d * NEG_L2_1E4_O256);
        const float rev  = __builtin_amdgcn_fractf(sf * invf * INV_2PI);
        pe[j] = (d & 1) ? __builtin_amdgcn_cosf(rev)
                        : __builtin_amdgcn_sinf(rev);
    }

    // --- add PE, stream out (nontemporal: never re-read) ---
    f4* out4 = (f4*)out;
#pragma unroll
    for (int b = 0; b < BATCH; ++b) {
        f4 v = e[b];
        v.x += pe[0];
        v.y += pe[1];
        v.z += pe[2];
        v.w += pe[3];
        __builtin_nontemporal_store(
            v, &out4[((size_t)b * SEQ + s) * (D_MODEL / 4) + tid]);
    }
}

extern "C" void kernel_launch(void* const* d_in, const int* in_sizes, int n_in,
                              void* d_out, int out_size, void* d_ws, size_t ws_size,
                              hipStream_t stream) {
    const int*   tokens = (const int*)d_in[0];    // [8,4096] int32
    const float* table  = (const float*)d_in[1];  // [32000,512] fp32
    float*       out    = (float*)d_out;          // [8,4096,512] fp32

    emb_pe_kernel<<<SEQ, 128, 0, stream>>>(tokens, table, out);
}